// Round 17
// baseline (798.250 us; speedup 1.0000x reference)
//
#include <hip/hip_runtime.h>
#include <hip/hip_bf16.h>
#include <cstdint>

#define DEVINL __device__ __forceinline__

using f32x4  = __attribute__((ext_vector_type(4))) float;
using short8 = __attribute__((ext_vector_type(8))) short;
using short4v = __attribute__((ext_vector_type(4))) short;

DEVINL float bf2f(__hip_bfloat16 h){ return __bfloat162float(h); }
DEVINL __hip_bfloat16 f2bf(float f){ return __float2bfloat16(f); }
DEVINL short bfbits(float f){ __hip_bfloat16 h = __float2bfloat16(f); short s; __builtin_memcpy(&s, &h, 2); return s; }
DEVINL float sb2f(short s){ uint32_t u = ((uint32_t)(uint16_t)s) << 16; float f; __builtin_memcpy(&f, &u, 4); return f; }

DEVINL void gl_lds16(const void* g, void* l){
  __builtin_amdgcn_global_load_lds((const __attribute__((address_space(1))) void*)g,
                                   (__attribute__((address_space(3))) void*)l, 16, 0, 0);
}

// ---------------- weight transpose + f32->bf16 cast: dst[C][R] = src[R][C] ----------------
__global__ __launch_bounds__(256) void wtrans(const float* __restrict__ src,
                                              __hip_bfloat16* __restrict__ dst,
                                              int R, int C){
  __shared__ float tile[32][33];
  const int tr0 = blockIdx.y*32, tc0 = blockIdx.x*32;
  const int t = threadIdx.x;
  const int lr = t >> 3, lc = (t & 7) * 4;
  float4 v = *(const float4*)(src + (size_t)(tr0+lr)*C + tc0 + lc);
  tile[lr][lc] = v.x; tile[lr][lc+1] = v.y; tile[lr][lc+2] = v.z; tile[lr][lc+3] = v.w;
  __syncthreads();
  short4v o;
  o[0] = bfbits(tile[lc+0][lr]);
  o[1] = bfbits(tile[lc+1][lr]);
  o[2] = bfbits(tile[lc+2][lr]);
  o[3] = bfbits(tile[lc+3][lr]);
  *(short4v*)(dst + (size_t)(tc0+lr)*R + tr0 + lc) = o;
}

// ---------------- LayerNorm (C=2048), one row per block, bf16 out ----------------
__global__ __launch_bounds__(256) void ln_k(const float* __restrict__ x,
                                            const float* __restrict__ w,
                                            const float* __restrict__ bia,
                                            __hip_bfloat16* __restrict__ out){
  const int row = blockIdx.x, t = threadIdx.x;
  const float* xr = x + (size_t)row*2048;
  float4 v0 = *(const float4*)(xr + t*4);
  float4 v1 = *(const float4*)(xr + 1024 + t*4);
  float s  = v0.x+v0.y+v0.z+v0.w + v1.x+v1.y+v1.z+v1.w;
  float ss = v0.x*v0.x+v0.y*v0.y+v0.z*v0.z+v0.w*v0.w
           + v1.x*v1.x+v1.y*v1.y+v1.z*v1.z+v1.w*v1.w;
  #pragma unroll
  for (int o=1;o<64;o<<=1){ s += __shfl_xor(s,o); ss += __shfl_xor(ss,o); }
  __shared__ float red[8];
  const int wv = t>>6, ln = t&63;
  if (ln==0){ red[wv]=s; red[4+wv]=ss; }
  __syncthreads();
  s = red[0]+red[1]+red[2]+red[3]; ss = red[4]+red[5]+red[6]+red[7];
  const float mu = s*(1.f/2048.f);
  const float inv = rsqrtf(ss*(1.f/2048.f) - mu*mu + 1e-5f);
  {
    float4 wv4 = *(const float4*)(w + t*4);
    float4 bv4 = *(const float4*)(bia + t*4);
    short4v o;
    o[0]=bfbits((v0.x-mu)*inv*wv4.x + bv4.x);
    o[1]=bfbits((v0.y-mu)*inv*wv4.y + bv4.y);
    o[2]=bfbits((v0.z-mu)*inv*wv4.z + bv4.z);
    o[3]=bfbits((v0.w-mu)*inv*wv4.w + bv4.w);
    *(short4v*)(out + (size_t)row*2048 + t*4) = o;
  }
  {
    float4 wv4 = *(const float4*)(w + 1024 + t*4);
    float4 bv4 = *(const float4*)(bia + 1024 + t*4);
    short4v o;
    o[0]=bfbits((v1.x-mu)*inv*wv4.x + bv4.x);
    o[1]=bfbits((v1.y-mu)*inv*wv4.y + bv4.y);
    o[2]=bfbits((v1.z-mu)*inv*wv4.z + bv4.z);
    o[3]=bfbits((v1.w-mu)*inv*wv4.w + bv4.w);
    *(short4v*)(out + (size_t)row*2048 + 1024 + t*4) = o;
  }
}

// ====== quad-buffered GEMM (r10/r15-proven): C[M,N]=A[M,K]*Bt[N,K]^T, BM x 256, BK=32 ======
// EPI 4: bf16   1: f32 + resid (in-place ok)
template<int EPI, int BM>
__global__ __launch_bounds__(512, 2) void gemmp(
    const __hip_bfloat16* __restrict__ A,
    const __hip_bfloat16* __restrict__ Bt,
    __hip_bfloat16* __restrict__ Cb,
    float* __restrict__ Cf,
    const float* __restrict__ resid,
    int M, int N, int K, int NTN)
{
  constexpr int MF    = BM/32;
  constexpr int LA    = BM/128;
  constexpr int ABY   = BM*64;
  constexpr int TILEB = ABY + 16384;
  extern __shared__ char smem[];
  const int tid = threadIdx.x, lane = tid & 63, wave = tid >> 6;
  const int l15 = lane & 15, l4 = lane >> 4;
  const int wm = wave >> 2, wn = wave & 3;

  const int nwg = gridDim.x;
  const int id  = blockIdx.x;
  const int swz = (id & 7) * (nwg >> 3) + (id >> 3);
  const int by = swz / NTN, bx = swz % NTN;
  const int row0 = by * BM, col0 = bx * 256;

  const __hip_bfloat16* srcA[LA]; int dstA[LA];
  #pragma unroll
  for (int g = 0; g < LA; ++g){
    const int c = g*512 + tid, r = c >> 2, s = c & 3;
    const int kbyte = (s*16) ^ (((r >> 1) & 3) << 4);
    srcA[g] = A + (size_t)(row0 + r)*K + (kbyte >> 1);
    dstA[g] = c*16;
  }
  const __hip_bfloat16* srcB[2]; int dstB[2];
  #pragma unroll
  for (int g = 0; g < 2; ++g){
    const int c = g*512 + tid, r = c >> 2, s = c & 3;
    const int kbyte = (s*16) ^ (((r >> 1) & 3) << 4);
    srcB[g] = Bt + (size_t)(col0 + r)*K + (kbyte >> 1);
    dstB[g] = c*16;
  }
  auto STAGE = [&](int bi, int kt){
    char* base = smem + bi*TILEB;
    #pragma unroll
    for (int g = 0; g < LA; ++g) gl_lds16(srcA[g] + kt*32, base + dstA[g]);
    #pragma unroll
    for (int g = 0; g < 2; ++g)  gl_lds16(srcB[g] + kt*32, base + ABY + dstB[g]);
  };

  const int rmask = ((l15 >> 1) & 3) << 4;
  int offA[MF], offB[4];
  #pragma unroll
  for (int m = 0; m < MF; ++m){
    const int r = wm*(BM/2) + m*16 + l15;
    offA[m] = r*64 + ((l4*16) ^ rmask);
  }
  #pragma unroll
  for (int n = 0; n < 4; ++n){
    const int r = wn*64 + n*16 + l15;
    offB[n] = r*64 + ((l4*16) ^ rmask);
  }

  f32x4 acc[MF][4] = {};
  const int NT = K >> 5;

  STAGE(0, 0); STAGE(1, 1); STAGE(2, 2);
  __builtin_amdgcn_sched_barrier(0);
  if constexpr (BM == 256) asm volatile("s_waitcnt vmcnt(8)" ::: "memory");
  else                     asm volatile("s_waitcnt vmcnt(6)" ::: "memory");
  __builtin_amdgcn_s_barrier();
  __builtin_amdgcn_sched_barrier(0);

  for (int t = 0; t < NT; ++t){
    const char* base = smem + (t & 3)*TILEB;
    if (t + 3 < NT) STAGE((t + 3) & 3, t + 3);
    short8 a[MF], b[4];
    #pragma unroll
    for (int m = 0; m < MF; ++m) a[m] = *(const short8*)(base + offA[m]);
    #pragma unroll
    for (int n = 0; n < 4; ++n)  b[n] = *(const short8*)(base + ABY + offB[n]);
    __builtin_amdgcn_s_setprio(1);
    #pragma unroll
    for (int m = 0; m < MF; ++m)
      #pragma unroll
      for (int n = 0; n < 4; ++n)
        acc[m][n] = __builtin_amdgcn_mfma_f32_16x16x32_bf16(a[m], b[n], acc[m][n], 0, 0, 0);
    __builtin_amdgcn_s_setprio(0);
    if (t + 3 < NT){
      if constexpr (BM == 256) asm volatile("s_waitcnt vmcnt(8)" ::: "memory");
      else                     asm volatile("s_waitcnt vmcnt(6)" ::: "memory");
    } else if (t + 2 < NT){
      if constexpr (BM == 256) asm volatile("s_waitcnt vmcnt(4)" ::: "memory");
      else                     asm volatile("s_waitcnt vmcnt(3)" ::: "memory");
    } else {
      asm volatile("s_waitcnt vmcnt(0)" ::: "memory");
    }
    __builtin_amdgcn_s_barrier();
    __builtin_amdgcn_sched_barrier(0);
  }

  #pragma unroll
  for (int m = 0; m < MF; ++m){
    const int r0 = row0 + wm*(BM/2) + m*16 + l4*4;
    #pragma unroll
    for (int n = 0; n < 4; ++n){
      const int c = col0 + wn*64 + n*16 + l15;
      #pragma unroll
      for (int j = 0; j < 4; ++j){
        const size_t idx = (size_t)(r0 + j)*N + c;
        const float v = acc[m][n][j];
        if constexpr (EPI == 1) Cf[idx] = v + resid[idx];
        else                    Cb[idx] = f2bf(v);
      }
    }
  }
}

// ====== fused SwiGLU GEMM: sub = silu(A*W1t^T) * (A*W2t^T), tile 256M x 128N ======
// NOW double-buffered 64KB -> 2 blocks/CU; depth-1 stage (t+1 at start of t), one
// vmcnt(0)+barrier per tile; the co-resident block's MFMA fills the drain.
__global__ __launch_bounds__(512, 2) void gemmf(
    const __hip_bfloat16* __restrict__ A,
    const __hip_bfloat16* __restrict__ B1t,
    const __hip_bfloat16* __restrict__ B2t,
    __hip_bfloat16* __restrict__ Cb,
    int M, int N, int K, int NTN)
{
  constexpr int ABY   = 16384;
  constexpr int TILEB = ABY + 16384;
  extern __shared__ char smem[];        // 2 * TILEB = 65536
  const int tid = threadIdx.x, lane = tid & 63, wave = tid >> 6;
  const int l15 = lane & 15, l4 = lane >> 4;
  const int wm = wave >> 2, wn = wave & 3;

  const int nwg = gridDim.x;
  const int id  = blockIdx.x;
  const int swz = (id & 7) * (nwg >> 3) + (id >> 3);
  const int by = swz / NTN, bx = swz % NTN;
  const int row0 = by * 256, col0 = bx * 128;

  const __hip_bfloat16* srcA[2]; int dstA[2];
  #pragma unroll
  for (int g = 0; g < 2; ++g){
    const int c = g*512 + tid, r = c >> 2, s = c & 3;
    const int kbyte = (s*16) ^ (((r >> 1) & 3) << 4);
    srcA[g] = A + (size_t)(row0 + r)*K + (kbyte >> 1);
    dstA[g] = c*16;
  }
  const __hip_bfloat16* srcB[2]; int dstB[2];
  #pragma unroll
  for (int g = 0; g < 2; ++g){
    const int c = g*512 + tid, r = c >> 2, s = c & 3;
    const int kbyte = (s*16) ^ (((r >> 1) & 3) << 4);
    const __hip_bfloat16* base = (r < 128) ? (B1t + (size_t)(col0 + r)*K)
                                           : (B2t + (size_t)(col0 + r - 128)*K);
    srcB[g] = base + (kbyte >> 1);
    dstB[g] = c*16;
  }
  auto STAGE = [&](int bi, int kt){
    char* base = smem + bi*TILEB;
    #pragma unroll
    for (int g = 0; g < 2; ++g) gl_lds16(srcA[g] + kt*32, base + dstA[g]);
    #pragma unroll
    for (int g = 0; g < 2; ++g) gl_lds16(srcB[g] + kt*32, base + ABY + dstB[g]);
  };

  const int rmask = ((l15 >> 1) & 3) << 4;
  int offA[8], offB[2][2];
  #pragma unroll
  for (int m = 0; m < 8; ++m){
    const int r = wm*128 + m*16 + l15;
    offA[m] = r*64 + ((l4*16) ^ rmask);
  }
  #pragma unroll
  for (int g = 0; g < 2; ++g)
    #pragma unroll
    for (int nf = 0; nf < 2; ++nf){
      const int r = g*128 + wn*32 + nf*16 + l15;
      offB[g][nf] = r*64 + ((l4*16) ^ rmask);
    }

  f32x4 acc[8][2][2] = {};
  const int NT = K >> 5;

  STAGE(0, 0);
  __builtin_amdgcn_sched_barrier(0);
  asm volatile("s_waitcnt vmcnt(0)" ::: "memory");
  __builtin_amdgcn_s_barrier();
  __builtin_amdgcn_sched_barrier(0);

  for (int t = 0; t < NT; ++t){
    const char* base = smem + (t & 1)*TILEB;
    if (t + 1 < NT) STAGE((t + 1) & 1, t + 1);
    short8 a[8], b[2][2];
    #pragma unroll
    for (int m = 0; m < 8; ++m) a[m] = *(const short8*)(base + offA[m]);
    #pragma unroll
    for (int g = 0; g < 2; ++g)
      #pragma unroll
      for (int nf = 0; nf < 2; ++nf) b[g][nf] = *(const short8*)(base + ABY + offB[g][nf]);
    __builtin_amdgcn_s_setprio(1);
    #pragma unroll
    for (int m = 0; m < 8; ++m)
      #pragma unroll
      for (int g = 0; g < 2; ++g)
        #pragma unroll
        for (int nf = 0; nf < 2; ++nf)
          acc[m][g][nf] = __builtin_amdgcn_mfma_f32_16x16x32_bf16(a[m], b[g][nf], acc[m][g][nf], 0, 0, 0);
    __builtin_amdgcn_s_setprio(0);
    asm volatile("s_waitcnt vmcnt(0)" ::: "memory");
    __builtin_amdgcn_s_barrier();
    __builtin_amdgcn_sched_barrier(0);
  }

  #pragma unroll
  for (int m = 0; m < 8; ++m){
    const int r0 = row0 + wm*128 + m*16 + l4*4;
    #pragma unroll
    for (int nf = 0; nf < 2; ++nf){
      const int c = col0 + wn*32 + nf*16 + l15;
      #pragma unroll
      for (int j = 0; j < 4; ++j){
        const float h1 = acc[m][0][nf][j];
        const float h2 = acc[m][1][nf][j];
        Cb[(size_t)(r0 + j)*N + c] = f2bf((h1 / (1.f + __expf(-h1))) * h2);
      }
    }
  }
}

// ------ RoPE + pack: qkv bf16 (B,T,3C) -> Q,K (BH,T,128) bf16, Vt (BH,128,T) bf16 ------
__global__ __launch_bounds__(256) void ropepack(
    const __hip_bfloat16* __restrict__ qkv, const float* __restrict__ cosT, const float* __restrict__ sinT,
    __hip_bfloat16* __restrict__ Qo, __hip_bfloat16* __restrict__ Ko, __hip_bfloat16* __restrict__ Vo)
{
  __shared__ short vt[128][72];
  const int bh = blockIdx.y, b = bh>>4, h = bh&15;
  const int t0 = blockIdx.x*64, tid = threadIdx.x;
  const int tr = tid>>2, q4 = tid&3;
  const int tg = t0 + tr;
  const __hip_bfloat16* base = qkv + ((size_t)(b*2048 + tg))*6144 + h*128;
  const int pp0 = q4*16;
  float cs[16], sn[16];
  #pragma unroll
  for (int i=0;i<4;i++){
    float4 c4 = *(const float4*)(cosT + (size_t)tg*64 + pp0 + i*4);
    float4 s4 = *(const float4*)(sinT + (size_t)tg*64 + pp0 + i*4);
    cs[i*4+0]=c4.x; cs[i*4+1]=c4.y; cs[i*4+2]=c4.z; cs[i*4+3]=c4.w;
    sn[i*4+0]=s4.x; sn[i*4+1]=s4.y; sn[i*4+2]=s4.z; sn[i*4+3]=s4.w;
  }
  #pragma unroll
  for (int qk=0; qk<2; ++qk){
    const __hip_bfloat16* src = base + qk*2048;
    __hip_bfloat16* dst = (qk==0 ? Qo : Ko) + ((size_t)bh*2048 + tg)*128 + pp0*2;
    short8 ov[4];
    short* o = (short*)ov;
    #pragma unroll
    for (int i=0;i<4;i++){
      short8 v = *(const short8*)(src + pp0*2 + i*8);
      #pragma unroll
      for (int j=0;j<4;j++){
        float xe = sb2f(v[2*j]), xo = sb2f(v[2*j+1]);
        float c = cs[4*i+j], s = sn[4*i+j];
        o[8*i+2*j]   = bfbits(xe*c - xo*s);
        o[8*i+2*j+1] = bfbits(xe*s + xo*c);
      }
    }
    #pragma unroll
    for (int i=0;i<4;i++) *(short8*)(dst + i*8) = ov[i];
  }
  const __hip_bfloat16* vsrc = base + 4096;
  const int vc0 = q4*32;
  #pragma unroll
  for (int i=0;i<4;i++){
    short8 v = *(const short8*)(vsrc + vc0 + i*8);
    #pragma unroll
    for (int j=0;j<8;j++) vt[vc0+i*8+j][tr] = v[j];
  }
  __syncthreads();
  const int d = tid>>1, th0 = (tid&1)*32;
  __hip_bfloat16* vdst = Vo + ((size_t)bh*128 + d)*2048 + t0 + th0;
  #pragma unroll
  for (int i=0;i<4;i++)
    *(short8*)(vdst + i*8) = *(const short8*)(&vt[d][th0 + i*8]);
}

// ----- Flash attention, causal: 4 waves/block, 1 supertile, 2 blocks/CU, KVBLK=64 -----
__global__ __launch_bounds__(256, 2) void attn_k(
    const __hip_bfloat16* __restrict__ Q,
    const __hip_bfloat16* __restrict__ K,
    const __hip_bfloat16* __restrict__ Vt,
    __hip_bfloat16* __restrict__ Y)
{
  extern __shared__ char lds[];
  const int bh = blockIdx.x, b = bh>>4, h = bh&15;
  const int by = blockIdx.y;
  const int qt = (by < 8) ? (15 - 2*by) : (2*(by - 8));
  const int tid = threadIdx.x, lane = tid&63, wave = tid>>6;
  const int qbase = qt*128 + wave*32;
  const int nsteps = 2*qt + 2;
  const __hip_bfloat16* Qh = Q + (size_t)bh*2048*128;
  const __hip_bfloat16* Kh = K + (size_t)bh*2048*128;
  const __hip_bfloat16* Vh = Vt + (size_t)bh*128*2048;
  char* plbase = lds + 49152 + wave*4608;
  const int l15 = lane & 15, l4 = lane >> 4;
  const int swzm = (l15 & 7) << 4;

  size_t ksrc[4], vsrc[4];
  int cdst[4];
  #pragma unroll
  for (int i = 0; i < 4; ++i){
    const int c = i*256 + tid;
    const int kr = c >> 4, kslot = c & 15;
    const int kcolb = (kslot*16) ^ ((kr & 7) << 4);
    ksrc[i] = (size_t)kr*128 + (kcolb >> 1);
    const int vr = c >> 3, vslot = c & 7;
    const int vcolb = (vslot*16) ^ ((vr & 7) << 4);
    vsrc[i] = (size_t)vr*2048 + (vcolb >> 1);
    cdst[i] = c*16;
  }
  auto STK = [&](int buf, int kv0){
    #pragma unroll
    for (int i = 0; i < 4; ++i)
      gl_lds16(Kh + (size_t)kv0*128 + ksrc[i], lds + buf*16384 + cdst[i]);
  };
  auto STV = [&](int kv0){
    #pragma unroll
    for (int i = 0; i < 4; ++i)
      gl_lds16(Vh + kv0 + vsrc[i], lds + 32768 + cdst[i]);
  };

  short8 qf[2][4];
  #pragma unroll
  for (int m=0;m<2;m++)
    #pragma unroll
    for (int kc=0;kc<4;kc++)
      qf[m][kc] = *(const short8*)(Qh + (size_t)(qbase + m*16 + l15)*128 + kc*32 + l4*8);

  short8 of;
  #pragma unroll
  for (int i=0;i<8;i++) of[i] = (l15==0) ? (short)0x3F80 : (short)0;

  f32x4 accO[2][9] = {};
  float mrow[2][4];
  #pragma unroll
  for (int m=0;m<2;m++)
    #pragma unroll
    for (int j=0;j<4;j++) mrow[m][j] = -1e30f;
  const float scale = 0.08838834764831845f;

  STK(0, 0);
  __builtin_amdgcn_sched_barrier(0);
  asm volatile("s_waitcnt vmcnt(0)" ::: "memory");
  __builtin_amdgcn_s_barrier();
  __builtin_amdgcn_sched_barrier(0);

  for (int s = 0; s < nsteps; ++s){
    const int kv0 = s*64;
    const char* kb = lds + (s&1)*16384;
    const char* vb = lds + 32768;
    const bool act = (kv0 <= qbase);
    const bool pfK = (s + 1 < nsteps);
    STV(kv0);
    if (pfK) STK((s+1)&1, kv0 + 64);
    __builtin_amdgcn_sched_barrier(0);
    float alpha_[2][4];
    if (act){
      const bool diag = (kv0 + 64 > qbase);
      const int kvrel = kv0 - qbase;
      f32x4 sc[2][4] = {};
      #pragma unroll
      for (int n=0;n<4;n++){
        short8 kf[4];
        #pragma unroll
        for (int kc=0;kc<4;kc++)
          kf[kc] = *(const short8*)(kb + (n*16 + l15)*256 + ((kc*64 + l4*16) ^ swzm));
        #pragma unroll
        for (int m=0;m<2;m++)
          #pragma unroll
          for (int kc=0;kc<4;kc++)
            sc[m][n] = __builtin_amdgcn_mfma_f32_16x16x32_bf16(qf[m][kc], kf[kc], sc[m][n], 0,0,0);
      }
      #pragma unroll
      for (int m=0;m<2;m++)
        #pragma unroll
        for (int j=0;j<4;j++){
          const int qr = 16*m + 4*l4 + j;
          float a[4];
          #pragma unroll
          for (int n=0;n<4;n++){
            a[n] = sc[m][n][j]*scale;
            if (diag && (kvrel + n*16 + l15 > qr)) a[n] = -1e30f;
          }
          float mx = fmaxf(fmaxf(a[0],a[1]), fmaxf(a[2],a[3]));
          #pragma unroll
          for (int o=1;o<16;o<<=1) mx = fmaxf(mx, __shfl_xor(mx, o));
          const float mn = fmaxf(mrow[m][j], mx);
          const float al = __expf(mrow[m][j] - mn);
          mrow[m][j] = mn;
          alpha_[m][j] = al;
          __hip_bfloat16* pr = (__hip_bfloat16*)(plbase + qr*144) + l15;
          #pragma unroll
          for (int n=0;n<4;n++) pr[n*16] = f2bf(__expf(a[n] - mn));
        }
      #pragma unroll
      for (int m=0;m<2;m++)
        #pragma unroll
        for (int db=0;db<9;db++)
          #pragma unroll
          for (int j=0;j<4;j++)
            accO[m][db][j] *= alpha_[m][j];
      asm volatile("s_waitcnt lgkmcnt(0)" ::: "memory");
      __builtin_amdgcn_sched_barrier(0);
    }
    if (pfK) asm volatile("s_waitcnt vmcnt(4)" ::: "memory");
    else     asm volatile("s_waitcnt vmcnt(0)" ::: "memory");
    __builtin_amdgcn_s_barrier();
    __builtin_amdgcn_sched_barrier(0);
    if (act){
      short8 pa[2][2];
      #pragma unroll
      for (int m=0;m<2;m++)
        #pragma unroll
        for (int ks=0;ks<2;ks++)
          pa[m][ks] = *(const short8*)(plbase + (m*16 + l15)*144 + ks*64 + l4*16);
      #pragma unroll
      for (int db=0;db<8;db++){
        #pragma unroll
        for (int ks=0;ks<2;ks++){
          short8 vf = *(const short8*)(vb + (db*16 + l15)*128 + ((ks*64 + l4*16) ^ swzm));
          #pragma unroll
          for (int m=0;m<2;m++)
            accO[m][db] = __builtin_amdgcn_mfma_f32_16x16x32_bf16(pa[m][ks], vf, accO[m][db], 0,0,0);
        }
      }
      #pragma unroll
      for (int ks=0;ks<2;ks++)
        #pragma unroll
        for (int m=0;m<2;m++)
          accO[m][8] = __builtin_amdgcn_mfma_f32_16x16x32_bf16(pa[m][ks], of, accO[m][8], 0,0,0);
    }
    __builtin_amdgcn_sched_barrier(0);
    asm volatile("s_waitcnt vmcnt(0)" ::: "memory");
    __builtin_amdgcn_s_barrier();
    __builtin_amdgcn_sched_barrier(0);
  }

  #pragma unroll
  for (int m=0;m<2;m++){
    float lr[4];
    #pragma unroll
    for (int j=0;j<4;j++) lr[j] = __shfl(accO[m][8][j], l4*16);
    #pragma unroll
    for (int db=0;db<8;db++)
      #pragma unroll
      for (int j=0;j<4;j++){
        const int tg = qbase + 16*m + 4*l4 + j;
        const int d  = 16*db + l15;
        Y[((size_t)b*2048 + tg)*2048 + h*128 + d] = f2bf(accO[m][db][j] / lr[j]);
      }
  }
}

// ---------------- launcher ----------------
extern "C" void kernel_launch(void* const* d_in, const int* in_sizes, int n_in,
                              void* d_out, int out_size, void* d_ws, size_t ws_size,
                              hipStream_t stream)
{
  const float* x    = (const float*)d_in[0];
  const float* cosT = (const float*)d_in[1];
  const float* sinT = (const float*)d_in[2];
  const float* ln1w = (const float*)d_in[3];
  const float* ln1b = (const float*)d_in[4];
  const float* ln2w = (const float*)d_in[5];
  const float* ln2b = (const float*)d_in[6];
  const float* Wqkv = (const float*)d_in[7];
  const float* Wo   = (const float*)d_in[8];
  const float* W1   = (const float*)d_in[9];
  const float* W2   = (const float*)d_in[10];
  const float* W3   = (const float*)d_in[11];
  float* out = (float*)d_out;

  if (ws_size < 150994944) return;
  char* ws = (char*)d_ws;
  __hip_bfloat16* WT    = (__hip_bfloat16*)(ws);
  __hip_bfloat16* W2T   = (__hip_bfloat16*)(ws + 33554432);
  __hip_bfloat16* WoT   = (__hip_bfloat16*)(ws + 50331648);
  __hip_bfloat16* abf   = (__hip_bfloat16*)(ws + 67108864);
  __hip_bfloat16* qkvb  = (__hip_bfloat16*)(ws + 83886080);
  __hip_bfloat16* sub   = (__hip_bfloat16*)(ws + 83886080);
  __hip_bfloat16* Qb    = (__hip_bfloat16*)(ws);
  __hip_bfloat16* Kb    = (__hip_bfloat16*)(ws + 16777216);
  __hip_bfloat16* Vtb   = (__hip_bfloat16*)(ws + 33554432);
  __hip_bfloat16* Yb    = (__hip_bfloat16*)(ws + 134217728);
  float*          x2    = out;

  hipFuncSetAttribute(reinterpret_cast<const void*>(&gemmp<4,128>),
                      hipFuncAttributeMaxDynamicSharedMemorySize, 98304);
  hipFuncSetAttribute(reinterpret_cast<const void*>(&gemmp<1,128>),
                      hipFuncAttributeMaxDynamicSharedMemorySize, 98304);
  hipFuncSetAttribute(reinterpret_cast<const void*>(&gemmf),
                      hipFuncAttributeMaxDynamicSharedMemorySize, 65536);
  hipFuncSetAttribute(reinterpret_cast<const void*>(&attn_k),
                      hipFuncAttributeMaxDynamicSharedMemorySize, 67584);

  ln_k<<<4096,256,0,stream>>>(x, ln1w, ln1b, abf);
  wtrans<<<dim3(192,64),256,0,stream>>>(Wqkv, WT, 2048, 6144);
  gemmp<4,128><<<768,512,98304,stream>>>(abf, WT, qkvb, nullptr, nullptr, 4096, 6144, 2048, 24);
  ropepack<<<dim3(32,32),256,0,stream>>>(qkvb, cosT, sinT, Qb, Kb, Vtb);
  attn_k<<<dim3(32,16),256,67584,stream>>>(Qb, Kb, Vtb, Yb);
  wtrans<<<dim3(64,64),256,0,stream>>>(Wo, WoT, 2048, 2048);
  gemmp<1,128><<<256,512,98304,stream>>>(Yb, WoT, nullptr, x2, x, 4096, 2048, 2048, 8);
  ln_k<<<4096,256,0,stream>>>(x2, ln2w, ln2b, abf);
  wtrans<<<dim3(256,64),256,0,stream>>>(W1, WT, 2048, 8192);
  wtrans<<<dim3(256,64),256,0,stream>>>(W2, W2T, 2048, 8192);
  gemmf<<<1024,512,65536,stream>>>(abf, WT, W2T, sub, 4096, 8192, 2048, 64);
  wtrans<<<dim3(64,256),256,0,stream>>>(W3, WT, 8192, 2048);
  gemmp<1,128><<<256,512,98304,stream>>>(sub, WT, nullptr, out, x2, 4096, 2048, 8192, 8);
}

// Round 18
// 790.141 us; speedup vs baseline: 1.0103x; 1.0103x over previous
//
#include <hip/hip_runtime.h>
#include <hip/hip_bf16.h>
#include <cstdint>

#define DEVINL __device__ __forceinline__

using f32x4  = __attribute__((ext_vector_type(4))) float;
using short8 = __attribute__((ext_vector_type(8))) short;
using short4v = __attribute__((ext_vector_type(4))) short;

DEVINL float bf2f(__hip_bfloat16 h){ return __bfloat162float(h); }
DEVINL __hip_bfloat16 f2bf(float f){ return __float2bfloat16(f); }
DEVINL short bfbits(float f){ __hip_bfloat16 h = __float2bfloat16(f); short s; __builtin_memcpy(&s, &h, 2); return s; }
DEVINL float sb2f(short s){ uint32_t u = ((uint32_t)(uint16_t)s) << 16; float f; __builtin_memcpy(&f, &u, 4); return f; }

DEVINL void gl_lds16(const void* g, void* l){
  __builtin_amdgcn_global_load_lds((const __attribute__((address_space(1))) void*)g,
                                   (__attribute__((address_space(3))) void*)l, 16, 0, 0);
}

// ---------------- weight transpose + f32->bf16 cast: dst[C][R] = src[R][C] ----------------
__global__ __launch_bounds__(256) void wtrans(const float* __restrict__ src,
                                              __hip_bfloat16* __restrict__ dst,
                                              int R, int C){
  __shared__ float tile[32][33];
  const int tr0 = blockIdx.y*32, tc0 = blockIdx.x*32;
  const int t = threadIdx.x;
  const int lr = t >> 3, lc = (t & 7) * 4;
  float4 v = *(const float4*)(src + (size_t)(tr0+lr)*C + tc0 + lc);
  tile[lr][lc] = v.x; tile[lr][lc+1] = v.y; tile[lr][lc+2] = v.z; tile[lr][lc+3] = v.w;
  __syncthreads();
  short4v o;
  o[0] = bfbits(tile[lc+0][lr]);
  o[1] = bfbits(tile[lc+1][lr]);
  o[2] = bfbits(tile[lc+2][lr]);
  o[3] = bfbits(tile[lc+3][lr]);
  *(short4v*)(dst + (size_t)(tc0+lr)*R + tr0 + lc) = o;
}

// ---------------- LayerNorm (C=2048), one row per block, bf16 out ----------------
__global__ __launch_bounds__(256) void ln_k(const float* __restrict__ x,
                                            const float* __restrict__ w,
                                            const float* __restrict__ bia,
                                            __hip_bfloat16* __restrict__ out){
  const int row = blockIdx.x, t = threadIdx.x;
  const float* xr = x + (size_t)row*2048;
  float4 v0 = *(const float4*)(xr + t*4);
  float4 v1 = *(const float4*)(xr + 1024 + t*4);
  float s  = v0.x+v0.y+v0.z+v0.w + v1.x+v1.y+v1.z+v1.w;
  float ss = v0.x*v0.x+v0.y*v0.y+v0.z*v0.z+v0.w*v0.w
           + v1.x*v1.x+v1.y*v1.y+v1.z*v1.z+v1.w*v1.w;
  #pragma unroll
  for (int o=1;o<64;o<<=1){ s += __shfl_xor(s,o); ss += __shfl_xor(ss,o); }
  __shared__ float red[8];
  const int wv = t>>6, ln = t&63;
  if (ln==0){ red[wv]=s; red[4+wv]=ss; }
  __syncthreads();
  s = red[0]+red[1]+red[2]+red[3]; ss = red[4]+red[5]+red[6]+red[7];
  const float mu = s*(1.f/2048.f);
  const float inv = rsqrtf(ss*(1.f/2048.f) - mu*mu + 1e-5f);
  {
    float4 wv4 = *(const float4*)(w + t*4);
    float4 bv4 = *(const float4*)(bia + t*4);
    short4v o;
    o[0]=bfbits((v0.x-mu)*inv*wv4.x + bv4.x);
    o[1]=bfbits((v0.y-mu)*inv*wv4.y + bv4.y);
    o[2]=bfbits((v0.z-mu)*inv*wv4.z + bv4.z);
    o[3]=bfbits((v0.w-mu)*inv*wv4.w + bv4.w);
    *(short4v*)(out + (size_t)row*2048 + t*4) = o;
  }
  {
    float4 wv4 = *(const float4*)(w + 1024 + t*4);
    float4 bv4 = *(const float4*)(bia + 1024 + t*4);
    short4v o;
    o[0]=bfbits((v1.x-mu)*inv*wv4.x + bv4.x);
    o[1]=bfbits((v1.y-mu)*inv*wv4.y + bv4.y);
    o[2]=bfbits((v1.z-mu)*inv*wv4.z + bv4.z);
    o[3]=bfbits((v1.w-mu)*inv*wv4.w + bv4.w);
    *(short4v*)(out + (size_t)row*2048 + 1024 + t*4) = o;
  }
}

// ====== quad-buffered GEMM (r10-proven): C[M,N]=A[M,K]*Bt[N,K]^T, BM x 256, BK=32 ======
// EPI 4: bf16   1: f32 + resid (in-place ok)
template<int EPI, int BM>
__global__ __launch_bounds__(512, 2) void gemmp(
    const __hip_bfloat16* __restrict__ A,
    const __hip_bfloat16* __restrict__ Bt,
    __hip_bfloat16* __restrict__ Cb,
    float* __restrict__ Cf,
    const float* __restrict__ resid,
    int M, int N, int K, int NTN)
{
  constexpr int MF    = BM/32;
  constexpr int LA    = BM/128;
  constexpr int ABY   = BM*64;
  constexpr int TILEB = ABY + 16384;
  extern __shared__ char smem[];
  const int tid = threadIdx.x, lane = tid & 63, wave = tid >> 6;
  const int l15 = lane & 15, l4 = lane >> 4;
  const int wm = wave >> 2, wn = wave & 3;

  const int nwg = gridDim.x;
  const int id  = blockIdx.x;
  const int swz = (id & 7) * (nwg >> 3) + (id >> 3);
  const int by = swz / NTN, bx = swz % NTN;
  const int row0 = by * BM, col0 = bx * 256;

  const __hip_bfloat16* srcA[LA]; int dstA[LA];
  #pragma unroll
  for (int g = 0; g < LA; ++g){
    const int c = g*512 + tid, r = c >> 2, s = c & 3;
    const int kbyte = (s*16) ^ (((r >> 1) & 3) << 4);
    srcA[g] = A + (size_t)(row0 + r)*K + (kbyte >> 1);
    dstA[g] = c*16;
  }
  const __hip_bfloat16* srcB[2]; int dstB[2];
  #pragma unroll
  for (int g = 0; g < 2; ++g){
    const int c = g*512 + tid, r = c >> 2, s = c & 3;
    const int kbyte = (s*16) ^ (((r >> 1) & 3) << 4);
    srcB[g] = Bt + (size_t)(col0 + r)*K + (kbyte >> 1);
    dstB[g] = c*16;
  }
  auto STAGE = [&](int bi, int kt){
    char* base = smem + bi*TILEB;
    #pragma unroll
    for (int g = 0; g < LA; ++g) gl_lds16(srcA[g] + kt*32, base + dstA[g]);
    #pragma unroll
    for (int g = 0; g < 2; ++g)  gl_lds16(srcB[g] + kt*32, base + ABY + dstB[g]);
  };

  const int rmask = ((l15 >> 1) & 3) << 4;
  int offA[MF], offB[4];
  #pragma unroll
  for (int m = 0; m < MF; ++m){
    const int r = wm*(BM/2) + m*16 + l15;
    offA[m] = r*64 + ((l4*16) ^ rmask);
  }
  #pragma unroll
  for (int n = 0; n < 4; ++n){
    const int r = wn*64 + n*16 + l15;
    offB[n] = r*64 + ((l4*16) ^ rmask);
  }

  f32x4 acc[MF][4] = {};
  const int NT = K >> 5;

  STAGE(0, 0); STAGE(1, 1); STAGE(2, 2);
  __builtin_amdgcn_sched_barrier(0);
  if constexpr (BM == 256) asm volatile("s_waitcnt vmcnt(8)" ::: "memory");
  else                     asm volatile("s_waitcnt vmcnt(6)" ::: "memory");
  __builtin_amdgcn_s_barrier();
  __builtin_amdgcn_sched_barrier(0);

  for (int t = 0; t < NT; ++t){
    const char* base = smem + (t & 3)*TILEB;
    if (t + 3 < NT) STAGE((t + 3) & 3, t + 3);
    short8 a[MF], b[4];
    #pragma unroll
    for (int m = 0; m < MF; ++m) a[m] = *(const short8*)(base + offA[m]);
    #pragma unroll
    for (int n = 0; n < 4; ++n)  b[n] = *(const short8*)(base + ABY + offB[n]);
    __builtin_amdgcn_s_setprio(1);
    #pragma unroll
    for (int m = 0; m < MF; ++m)
      #pragma unroll
      for (int n = 0; n < 4; ++n)
        acc[m][n] = __builtin_amdgcn_mfma_f32_16x16x32_bf16(a[m], b[n], acc[m][n], 0, 0, 0);
    __builtin_amdgcn_s_setprio(0);
    if (t + 3 < NT){
      if constexpr (BM == 256) asm volatile("s_waitcnt vmcnt(8)" ::: "memory");
      else                     asm volatile("s_waitcnt vmcnt(6)" ::: "memory");
    } else if (t + 2 < NT){
      if constexpr (BM == 256) asm volatile("s_waitcnt vmcnt(4)" ::: "memory");
      else                     asm volatile("s_waitcnt vmcnt(3)" ::: "memory");
    } else {
      asm volatile("s_waitcnt vmcnt(0)" ::: "memory");
    }
    __builtin_amdgcn_s_barrier();
    __builtin_amdgcn_sched_barrier(0);
  }

  #pragma unroll
  for (int m = 0; m < MF; ++m){
    const int r0 = row0 + wm*(BM/2) + m*16 + l4*4;
    #pragma unroll
    for (int n = 0; n < 4; ++n){
      const int c = col0 + wn*64 + n*16 + l15;
      #pragma unroll
      for (int j = 0; j < 4; ++j){
        const size_t idx = (size_t)(r0 + j)*N + c;
        const float v = acc[m][n][j];
        if constexpr (EPI == 1) Cf[idx] = v + resid[idx];
        else                    Cb[idx] = f2bf(v);
      }
    }
  }
}

// ====== fused SwiGLU GEMM (r13-proven): sub = silu(A*W1t^T) * (A*W2t^T), 256M x 128N ======
// Quad-buffered 128KB, BK=32, dual-gate B-tile (256 rows), in-register silu(h1)*h2.
__global__ __launch_bounds__(512, 2) void gemmf(
    const __hip_bfloat16* __restrict__ A,
    const __hip_bfloat16* __restrict__ B1t,
    const __hip_bfloat16* __restrict__ B2t,
    __hip_bfloat16* __restrict__ Cb,
    int M, int N, int K, int NTN)
{
  constexpr int ABY   = 16384;
  constexpr int TILEB = ABY + 16384;
  extern __shared__ char smem[];        // 4 * TILEB = 131072
  const int tid = threadIdx.x, lane = tid & 63, wave = tid >> 6;
  const int l15 = lane & 15, l4 = lane >> 4;
  const int wm = wave >> 2, wn = wave & 3;

  const int nwg = gridDim.x;
  const int id  = blockIdx.x;
  const int swz = (id & 7) * (nwg >> 3) + (id >> 3);
  const int by = swz / NTN, bx = swz % NTN;
  const int row0 = by * 256, col0 = bx * 128;

  const __hip_bfloat16* srcA[2]; int dstA[2];
  #pragma unroll
  for (int g = 0; g < 2; ++g){
    const int c = g*512 + tid, r = c >> 2, s = c & 3;
    const int kbyte = (s*16) ^ (((r >> 1) & 3) << 4);
    srcA[g] = A + (size_t)(row0 + r)*K + (kbyte >> 1);
    dstA[g] = c*16;
  }
  const __hip_bfloat16* srcB[2]; int dstB[2];
  #pragma unroll
  for (int g = 0; g < 2; ++g){
    const int c = g*512 + tid, r = c >> 2, s = c & 3;
    const int kbyte = (s*16) ^ (((r >> 1) & 3) << 4);
    const __hip_bfloat16* base = (r < 128) ? (B1t + (size_t)(col0 + r)*K)
                                           : (B2t + (size_t)(col0 + r - 128)*K);
    srcB[g] = base + (kbyte >> 1);
    dstB[g] = c*16;
  }
  auto STAGE = [&](int bi, int kt){
    char* base = smem + bi*TILEB;
    #pragma unroll
    for (int g = 0; g < 2; ++g) gl_lds16(srcA[g] + kt*32, base + dstA[g]);
    #pragma unroll
    for (int g = 0; g < 2; ++g) gl_lds16(srcB[g] + kt*32, base + ABY + dstB[g]);
  };

  const int rmask = ((l15 >> 1) & 3) << 4;
  int offA[8], offB[2][2];
  #pragma unroll
  for (int m = 0; m < 8; ++m){
    const int r = wm*128 + m*16 + l15;
    offA[m] = r*64 + ((l4*16) ^ rmask);
  }
  #pragma unroll
  for (int g = 0; g < 2; ++g)
    #pragma unroll
    for (int nf = 0; nf < 2; ++nf){
      const int r = g*128 + wn*32 + nf*16 + l15;
      offB[g][nf] = r*64 + ((l4*16) ^ rmask);
    }

  f32x4 acc[8][2][2] = {};
  const int NT = K >> 5;

  STAGE(0, 0); STAGE(1, 1); STAGE(2, 2);
  __builtin_amdgcn_sched_barrier(0);
  asm volatile("s_waitcnt vmcnt(8)" ::: "memory");
  __builtin_amdgcn_s_barrier();
  __builtin_amdgcn_sched_barrier(0);

  for (int t = 0; t < NT; ++t){
    const char* base = smem + (t & 3)*TILEB;
    if (t + 3 < NT) STAGE((t + 3) & 3, t + 3);
    short8 a[8], b[2][2];
    #pragma unroll
    for (int m = 0; m < 8; ++m) a[m] = *(const short8*)(base + offA[m]);
    #pragma unroll
    for (int g = 0; g < 2; ++g)
      #pragma unroll
      for (int nf = 0; nf < 2; ++nf) b[g][nf] = *(const short8*)(base + ABY + offB[g][nf]);
    __builtin_amdgcn_s_setprio(1);
    #pragma unroll
    for (int m = 0; m < 8; ++m)
      #pragma unroll
      for (int g = 0; g < 2; ++g)
        #pragma unroll
        for (int nf = 0; nf < 2; ++nf)
          acc[m][g][nf] = __builtin_amdgcn_mfma_f32_16x16x32_bf16(a[m], b[g][nf], acc[m][g][nf], 0, 0, 0);
    __builtin_amdgcn_s_setprio(0);
    if (t + 3 < NT)      asm volatile("s_waitcnt vmcnt(8)" ::: "memory");
    else if (t + 2 < NT) asm volatile("s_waitcnt vmcnt(4)" ::: "memory");
    else                 asm volatile("s_waitcnt vmcnt(0)" ::: "memory");
    __builtin_amdgcn_s_barrier();
    __builtin_amdgcn_sched_barrier(0);
  }

  #pragma unroll
  for (int m = 0; m < 8; ++m){
    const int r0 = row0 + wm*128 + m*16 + l4*4;
    #pragma unroll
    for (int nf = 0; nf < 2; ++nf){
      const int c = col0 + wn*32 + nf*16 + l15;
      #pragma unroll
      for (int j = 0; j < 4; ++j){
        const float h1 = acc[m][0][nf][j];
        const float h2 = acc[m][1][nf][j];
        Cb[(size_t)(r0 + j)*N + c] = f2bf((h1 / (1.f + __expf(-h1))) * h2);
      }
    }
  }
}

// ------ RoPE + pack: qkv bf16 (B,T,3C) -> Q,K (BH,T,128) bf16, Vt (BH,128,T) bf16 ------
__global__ __launch_bounds__(256) void ropepack(
    const __hip_bfloat16* __restrict__ qkv, const float* __restrict__ cosT, const float* __restrict__ sinT,
    __hip_bfloat16* __restrict__ Qo, __hip_bfloat16* __restrict__ Ko, __hip_bfloat16* __restrict__ Vo)
{
  __shared__ short vt[128][72];
  const int bh = blockIdx.y, b = bh>>4, h = bh&15;
  const int t0 = blockIdx.x*64, tid = threadIdx.x;
  const int tr = tid>>2, q4 = tid&3;
  const int tg = t0 + tr;
  const __hip_bfloat16* base = qkv + ((size_t)(b*2048 + tg))*6144 + h*128;
  const int pp0 = q4*16;
  float cs[16], sn[16];
  #pragma unroll
  for (int i=0;i<4;i++){
    float4 c4 = *(const float4*)(cosT + (size_t)tg*64 + pp0 + i*4);
    float4 s4 = *(const float4*)(sinT + (size_t)tg*64 + pp0 + i*4);
    cs[i*4+0]=c4.x; cs[i*4+1]=c4.y; cs[i*4+2]=c4.z; cs[i*4+3]=c4.w;
    sn[i*4+0]=s4.x; sn[i*4+1]=s4.y; sn[i*4+2]=s4.z; sn[i*4+3]=s4.w;
  }
  #pragma unroll
  for (int qk=0; qk<2; ++qk){
    const __hip_bfloat16* src = base + qk*2048;
    __hip_bfloat16* dst = (qk==0 ? Qo : Ko) + ((size_t)bh*2048 + tg)*128 + pp0*2;
    short8 ov[4];
    short* o = (short*)ov;
    #pragma unroll
    for (int i=0;i<4;i++){
      short8 v = *(const short8*)(src + pp0*2 + i*8);
      #pragma unroll
      for (int j=0;j<4;j++){
        float xe = sb2f(v[2*j]), xo = sb2f(v[2*j+1]);
        float c = cs[4*i+j], s = sn[4*i+j];
        o[8*i+2*j]   = bfbits(xe*c - xo*s);
        o[8*i+2*j+1] = bfbits(xe*s + xo*c);
      }
    }
    #pragma unroll
    for (int i=0;i<4;i++) *(short8*)(dst + i*8) = ov[i];
  }
  const __hip_bfloat16* vsrc = base + 4096;
  const int vc0 = q4*32;
  #pragma unroll
  for (int i=0;i<4;i++){
    short8 v = *(const short8*)(vsrc + vc0 + i*8);
    #pragma unroll
    for (int j=0;j<8;j++) vt[vc0+i*8+j][tr] = v[j];
  }
  __syncthreads();
  const int d = tid>>1, th0 = (tid&1)*32;
  __hip_bfloat16* vdst = Vo + ((size_t)bh*128 + d)*2048 + t0 + th0;
  #pragma unroll
  for (int i=0;i<4;i++)
    *(short8*)(vdst + i*8) = *(const short8*)(&vt[d][th0 + i*8]);
}

// ----- Flash attention, causal (r15-proven): 4 waves/block, 2 blocks/CU, KVBLK=64 -----
__global__ __launch_bounds__(256, 2) void attn_k(
    const __hip_bfloat16* __restrict__ Q,
    const __hip_bfloat16* __restrict__ K,
    const __hip_bfloat16* __restrict__ Vt,
    __hip_bfloat16* __restrict__ Y)
{
  extern __shared__ char lds[];
  const int bh = blockIdx.x, b = bh>>4, h = bh&15;
  const int by = blockIdx.y;
  const int qt = (by < 8) ? (15 - 2*by) : (2*(by - 8));
  const int tid = threadIdx.x, lane = tid&63, wave = tid>>6;
  const int qbase = qt*128 + wave*32;
  const int nsteps = 2*qt + 2;
  const __hip_bfloat16* Qh = Q + (size_t)bh*2048*128;
  const __hip_bfloat16* Kh = K + (size_t)bh*2048*128;
  const __hip_bfloat16* Vh = Vt + (size_t)bh*128*2048;
  char* plbase = lds + 49152 + wave*4608;
  const int l15 = lane & 15, l4 = lane >> 4;
  const int swzm = (l15 & 7) << 4;

  size_t ksrc[4], vsrc[4];
  int cdst[4];
  #pragma unroll
  for (int i = 0; i < 4; ++i){
    const int c = i*256 + tid;
    const int kr = c >> 4, kslot = c & 15;
    const int kcolb = (kslot*16) ^ ((kr & 7) << 4);
    ksrc[i] = (size_t)kr*128 + (kcolb >> 1);
    const int vr = c >> 3, vslot = c & 7;
    const int vcolb = (vslot*16) ^ ((vr & 7) << 4);
    vsrc[i] = (size_t)vr*2048 + (vcolb >> 1);
    cdst[i] = c*16;
  }
  auto STK = [&](int buf, int kv0){
    #pragma unroll
    for (int i = 0; i < 4; ++i)
      gl_lds16(Kh + (size_t)kv0*128 + ksrc[i], lds + buf*16384 + cdst[i]);
  };
  auto STV = [&](int kv0){
    #pragma unroll
    for (int i = 0; i < 4; ++i)
      gl_lds16(Vh + kv0 + vsrc[i], lds + 32768 + cdst[i]);
  };

  short8 qf[2][4];
  #pragma unroll
  for (int m=0;m<2;m++)
    #pragma unroll
    for (int kc=0;kc<4;kc++)
      qf[m][kc] = *(const short8*)(Qh + (size_t)(qbase + m*16 + l15)*128 + kc*32 + l4*8);

  short8 of;
  #pragma unroll
  for (int i=0;i<8;i++) of[i] = (l15==0) ? (short)0x3F80 : (short)0;

  f32x4 accO[2][9] = {};
  float mrow[2][4];
  #pragma unroll
  for (int m=0;m<2;m++)
    #pragma unroll
    for (int j=0;j<4;j++) mrow[m][j] = -1e30f;
  const float scale = 0.08838834764831845f;

  STK(0, 0);
  __builtin_amdgcn_sched_barrier(0);
  asm volatile("s_waitcnt vmcnt(0)" ::: "memory");
  __builtin_amdgcn_s_barrier();
  __builtin_amdgcn_sched_barrier(0);

  for (int s = 0; s < nsteps; ++s){
    const int kv0 = s*64;
    const char* kb = lds + (s&1)*16384;
    const char* vb = lds + 32768;
    const bool act = (kv0 <= qbase);
    const bool pfK = (s + 1 < nsteps);
    STV(kv0);
    if (pfK) STK((s+1)&1, kv0 + 64);
    __builtin_amdgcn_sched_barrier(0);
    float alpha_[2][4];
    if (act){
      const bool diag = (kv0 + 64 > qbase);
      const int kvrel = kv0 - qbase;
      f32x4 sc[2][4] = {};
      #pragma unroll
      for (int n=0;n<4;n++){
        short8 kf[4];
        #pragma unroll
        for (int kc=0;kc<4;kc++)
          kf[kc] = *(const short8*)(kb + (n*16 + l15)*256 + ((kc*64 + l4*16) ^ swzm));
        #pragma unroll
        for (int m=0;m<2;m++)
          #pragma unroll
          for (int kc=0;kc<4;kc++)
            sc[m][n] = __builtin_amdgcn_mfma_f32_16x16x32_bf16(qf[m][kc], kf[kc], sc[m][n], 0,0,0);
      }
      #pragma unroll
      for (int m=0;m<2;m++)
        #pragma unroll
        for (int j=0;j<4;j++){
          const int qr = 16*m + 4*l4 + j;
          float a[4];
          #pragma unroll
          for (int n=0;n<4;n++){
            a[n] = sc[m][n][j]*scale;
            if (diag && (kvrel + n*16 + l15 > qr)) a[n] = -1e30f;
          }
          float mx = fmaxf(fmaxf(a[0],a[1]), fmaxf(a[2],a[3]));
          #pragma unroll
          for (int o=1;o<16;o<<=1) mx = fmaxf(mx, __shfl_xor(mx, o));
          const float mn = fmaxf(mrow[m][j], mx);
          const float al = __expf(mrow[m][j] - mn);
          mrow[m][j] = mn;
          alpha_[m][j] = al;
          __hip_bfloat16* pr = (__hip_bfloat16*)(plbase + qr*144) + l15;
          #pragma unroll
          for (int n=0;n<4;n++) pr[n*16] = f2bf(__expf(a[n] - mn));
        }
      #pragma unroll
      for (int m=0;m<2;m++)
        #pragma unroll
        for (int db=0;db<9;db++)
          #pragma unroll
          for (int j=0;j<4;j++)
            accO[m][db][j] *= alpha_[m][j];
      asm volatile("s_waitcnt lgkmcnt(0)" ::: "memory");
      __builtin_amdgcn_sched_barrier(0);
    }
    if (pfK) asm volatile("s_waitcnt vmcnt(4)" ::: "memory");
    else     asm volatile("s_waitcnt vmcnt(0)" ::: "memory");
    __builtin_amdgcn_s_barrier();
    __builtin_amdgcn_sched_barrier(0);
    if (act){
      short8 pa[2][2];
      #pragma unroll
      for (int m=0;m<2;m++)
        #pragma unroll
        for (int ks=0;ks<2;ks++)
          pa[m][ks] = *(const short8*)(plbase + (m*16 + l15)*144 + ks*64 + l4*16);
      #pragma unroll
      for (int db=0;db<8;db++){
        #pragma unroll
        for (int ks=0;ks<2;ks++){
          short8 vf = *(const short8*)(vb + (db*16 + l15)*128 + ((ks*64 + l4*16) ^ swzm));
          #pragma unroll
          for (int m=0;m<2;m++)
            accO[m][db] = __builtin_amdgcn_mfma_f32_16x16x32_bf16(pa[m][ks], vf, accO[m][db], 0,0,0);
        }
      }
      #pragma unroll
      for (int ks=0;ks<2;ks++)
        #pragma unroll
        for (int m=0;m<2;m++)
          accO[m][8] = __builtin_amdgcn_mfma_f32_16x16x32_bf16(pa[m][ks], of, accO[m][8], 0,0,0);
    }
    __builtin_amdgcn_sched_barrier(0);
    asm volatile("s_waitcnt vmcnt(0)" ::: "memory");
    __builtin_amdgcn_s_barrier();
    __builtin_amdgcn_sched_barrier(0);
  }

  #pragma unroll
  for (int m=0;m<2;m++){
    float lr[4];
    #pragma unroll
    for (int j=0;j<4;j++) lr[j] = __shfl(accO[m][8][j], l4*16);
    #pragma unroll
    for (int db=0;db<8;db++)
      #pragma unroll
      for (int j=0;j<4;j++){
        const int tg = qbase + 16*m + 4*l4 + j;
        const int d  = 16*db + l15;
        Y[((size_t)b*2048 + tg)*2048 + h*128 + d] = f2bf(accO[m][db][j] / lr[j]);
      }
  }
}

// ---------------- launcher ----------------
extern "C" void kernel_launch(void* const* d_in, const int* in_sizes, int n_in,
                              void* d_out, int out_size, void* d_ws, size_t ws_size,
                              hipStream_t stream)
{
  const float* x    = (const float*)d_in[0];
  const float* cosT = (const float*)d_in[1];
  const float* sinT = (const float*)d_in[2];
  const float* ln1w = (const float*)d_in[3];
  const float* ln1b = (const float*)d_in[4];
  const float* ln2w = (const float*)d_in[5];
  const float* ln2b = (const float*)d_in[6];
  const float* Wqkv = (const float*)d_in[7];
  const float* Wo   = (const float*)d_in[8];
  const float* W1   = (const float*)d_in[9];
  const float* W2   = (const float*)d_in[10];
  const float* W3   = (const float*)d_in[11];
  float* out = (float*)d_out;

  if (ws_size < 150994944) return;
  char* ws = (char*)d_ws;
  __hip_bfloat16* WT    = (__hip_bfloat16*)(ws);
  __hip_bfloat16* W2T   = (__hip_bfloat16*)(ws + 33554432);
  __hip_bfloat16* WoT   = (__hip_bfloat16*)(ws + 50331648);
  __hip_bfloat16* abf   = (__hip_bfloat16*)(ws + 67108864);
  __hip_bfloat16* qkvb  = (__hip_bfloat16*)(ws + 83886080);
  __hip_bfloat16* sub   = (__hip_bfloat16*)(ws + 83886080);
  __hip_bfloat16* Qb    = (__hip_bfloat16*)(ws);
  __hip_bfloat16* Kb    = (__hip_bfloat16*)(ws + 16777216);
  __hip_bfloat16* Vtb   = (__hip_bfloat16*)(ws + 33554432);
  __hip_bfloat16* Yb    = (__hip_bfloat16*)(ws + 134217728);
  float*          x2    = out;

  hipFuncSetAttribute(reinterpret_cast<const void*>(&gemmp<4,128>),
                      hipFuncAttributeMaxDynamicSharedMemorySize, 98304);
  hipFuncSetAttribute(reinterpret_cast<const void*>(&gemmp<1,128>),
                      hipFuncAttributeMaxDynamicSharedMemorySize, 98304);
  hipFuncSetAttribute(reinterpret_cast<const void*>(&gemmf),
                      hipFuncAttributeMaxDynamicSharedMemorySize, 131072);
  hipFuncSetAttribute(reinterpret_cast<const void*>(&attn_k),
                      hipFuncAttributeMaxDynamicSharedMemorySize, 67584);

  ln_k<<<4096,256,0,stream>>>(x, ln1w, ln1b, abf);
  wtrans<<<dim3(192,64),256,0,stream>>>(Wqkv, WT, 2048, 6144);
  gemmp<4,128><<<768,512,98304,stream>>>(abf, WT, qkvb, nullptr, nullptr, 4096, 6144, 2048, 24);
  ropepack<<<dim3(32,32),256,0,stream>>>(qkvb, cosT, sinT, Qb, Kb, Vtb);
  attn_k<<<dim3(32,16),256,67584,stream>>>(Qb, Kb, Vtb, Yb);
  wtrans<<<dim3(64,64),256,0,stream>>>(Wo, WoT, 2048, 2048);
  gemmp<1,128><<<256,512,98304,stream>>>(Yb, WoT, nullptr, x2, x, 4096, 2048, 2048, 8);
  ln_k<<<4096,256,0,stream>>>(x2, ln2w, ln2b, abf);
  wtrans<<<dim3(256,64),256,0,stream>>>(W1, WT, 2048, 8192);
  wtrans<<<dim3(256,64),256,0,stream>>>(W2, W2T, 2048, 8192);
  gemmf<<<1024,512,131072,stream>>>(abf, WT, W2T, sub, 4096, 8192, 2048, 64);
  wtrans<<<dim3(64,256),256,0,stream>>>(W3, WT, 8192, 2048);
  gemmp<1,128><<<256,512,98304,stream>>>(sub, WT, nullptr, out, x2, 4096, 2048, 8192, 8);
}